// Round 6
// baseline (154.769 us; speedup 1.0000x reference)
//
#include <hip/hip_runtime.h>
#include <hip/hip_bf16.h>

#define B_  4
#define LQ  512
#define LK  512
#define D_  128
#define H_  128
#define TQ  2          // q-rows per attn block

#define TWO_LOG2E 2.885390081777927f   // 2*log2(e)
#define LOG2E     1.442695040888963f

__device__ __forceinline__ float fexp2(float x) {
#if __has_builtin(__builtin_amdgcn_exp2f)
  return __builtin_amdgcn_exp2f(x);     // v_exp_f32 (native exp2)
#else
  return exp2f(x);
#endif
}
__device__ __forceinline__ float frcp(float x) {
#if __has_builtin(__builtin_amdgcn_rcpf)
  return __builtin_amdgcn_rcpf(x);      // v_rcp_f32
#else
  return __fdividef(1.0f, x);
#endif
}

// 8 rows per block, 256 threads.
// Rows [0, B*LQ) -> qproj row-major [row][h].
// Rows [B*LQ, ..) -> kT TRANSPOSED [b][h][k] (coalesced k-reads in attn).
// Outputs pre-scaled by 2*log2(e) so score kernel feeds v_exp directly.
__global__ __launch_bounds__(256) void proj_kernel(
    const float* __restrict__ queries, const float* __restrict__ keys,
    const float* __restrict__ Wq, const float* __restrict__ Wk,
    float* __restrict__ qproj, float* __restrict__ kT) {
  __shared__ float s_x[8][D_];
  int r0 = blockIdx.x * 8;
  bool qside = r0 < B_ * LQ;
  const float* X = qside ? queries : keys;
  const float* W = qside ? Wq : Wk;
  int rb = qside ? r0 : r0 - B_ * LQ;
  int tid = threadIdx.x;
  for (int i = tid; i < 8 * D_; i += 256)
    s_x[i >> 7][i & 127] = X[(size_t)(rb + (i >> 7)) * D_ + (i & 127)];
  __syncthreads();
  int h = tid & 127, rh = tid >> 7;    // rh selects rows rh*4 .. rh*4+3
  float a0 = 0.f, a1 = 0.f, a2 = 0.f, a3 = 0.f;
  #pragma unroll 8
  for (int d = 0; d < D_; ++d) {
    float w = W[d * H_ + h];           // coalesced; W is L2-hot (64 KB)
    a0 += s_x[rh * 4 + 0][d] * w;      // LDS broadcasts
    a1 += s_x[rh * 4 + 1][d] * w;
    a2 += s_x[rh * 4 + 2][d] * w;
    a3 += s_x[rh * 4 + 3][d] * w;
  }
  if (qside) {
    qproj[(size_t)(rb + rh * 4 + 0) * H_ + h] = a0 * TWO_LOG2E;
    qproj[(size_t)(rb + rh * 4 + 1) * H_ + h] = a1 * TWO_LOG2E;
    qproj[(size_t)(rb + rh * 4 + 2) * H_ + h] = a2 * TWO_LOG2E;
    qproj[(size_t)(rb + rh * 4 + 3) * H_ + h] = a3 * TWO_LOG2E;
  } else {
    int b = rb >> 9, kk = (rb & 511) + rh * 4;   // LK = 512
    float* dst = kT + ((size_t)b * H_ + h) * LK + kk;
    dst[0] = a0 * TWO_LOG2E;   // scatter; only 1 MB total
    dst[1] = a1 * TWO_LOG2E;
    dst[2] = a2 * TWO_LOG2E;
    dst[3] = a3 * TWO_LOG2E;
  }
}

// One block per (qtile, batch). 512 threads = 8 waves; thread owns ONE k column.
// Grid (LQ/TQ, B): batch is the SLOW dim so resident blocks per CU span all
// batches -> per-CU work is balanced despite random vlen.
// Target: VGPR <= 64 so 4 blocks/CU (32 waves, 100% occupancy).
__global__ __launch_bounds__(512) void attn_kernel(
    const float* __restrict__ qproj, const float* __restrict__ kT,
    const float* __restrict__ values, const int* __restrict__ vlen_arr,
    const float* __restrict__ wv, const float* __restrict__ Wo,
    float* __restrict__ out) {
  int b  = blockIdx.y;
  int q0 = blockIdx.x * TQ;
  int tid = threadIdx.x;

  __shared__ float s_q[TQ][H_];        // 1 KB   (pre-scaled q rows)
  __shared__ float s_wv[H_];           // 0.5 KB
  __shared__ float s_sc[TQ][LK];       // 4 KB   scores -> weights
  __shared__ float s_po[4][TQ][D_];    // 4 KB   PV partials (4 k-chunks)

  if (tid < TQ * H_)
    s_q[tid >> 7][tid & 127] = qproj[(size_t)(b * LQ + q0 + (tid >> 7)) * H_ + (tid & 127)];
  else if (tid < TQ * H_ + H_)
    s_wv[tid - TQ * H_] = wv[tid - TQ * H_];
  __syncthreads();
  int vlen = vlen_arr[b];

  const float4* wv4p = (const float4*)s_wv;
  float sum_wv = 0.f;
  #pragma unroll
  for (int j = 0; j < H_ / 4; ++j) {
    float4 t4 = wv4p[j];
    sum_wv += t4.x + t4.y + t4.z + t4.w;
  }

  // ---- scores: thread owns k = tid; NO barriers in this phase ----
  // score = sum_wv - 2 * sum_h wv_h / (exp2(q'_h + k'_h) + 1)   [tanh identity]
  int k = tid;
  if (k < vlen) {            // waves fully past vlen skip via execz, park at barrier
    const float* kcol = kT + ((size_t)b * H_) * LK + k;   // stride LK per h
    const float4* qap = (const float4*)s_q[0];
    const float4* qbp = (const float4*)s_q[1];
    float acc0 = 0.f, acc1 = 0.f;
    #pragma unroll 4
    for (int h4 = 0; h4 < H_ / 4; ++h4) {
      float kv0 = kcol[(size_t)(4 * h4 + 0) * LK];   // 256B/wave coalesced, L2-hot
      float kv1 = kcol[(size_t)(4 * h4 + 1) * LK];
      float kv2 = kcol[(size_t)(4 * h4 + 2) * LK];
      float kv3 = kcol[(size_t)(4 * h4 + 3) * LK];
      float4 w4 = wv4p[h4];                          // LDS broadcasts
      float4 qa = qap[h4];
      float4 qb = qbp[h4];
      acc0 = fmaf(w4.x, frcp(fexp2(qa.x + kv0) + 1.f), acc0);
      acc1 = fmaf(w4.x, frcp(fexp2(qb.x + kv0) + 1.f), acc1);
      acc0 = fmaf(w4.y, frcp(fexp2(qa.y + kv1) + 1.f), acc0);
      acc1 = fmaf(w4.y, frcp(fexp2(qb.y + kv1) + 1.f), acc1);
      acc0 = fmaf(w4.z, frcp(fexp2(qa.z + kv2) + 1.f), acc0);
      acc1 = fmaf(w4.z, frcp(fexp2(qb.z + kv2) + 1.f), acc1);
      acc0 = fmaf(w4.w, frcp(fexp2(qa.w + kv3) + 1.f), acc0);
      acc1 = fmaf(w4.w, frcp(fexp2(qb.w + kv3) + 1.f), acc1);
    }
    s_sc[0][k] = fmaf(-2.f, acc0, sum_wv);
    s_sc[1][k] = fmaf(-2.f, acc1, sum_wv);
  } else {
    s_sc[0][k] = -1.0e6f;
    s_sc[1][k] = -1.0e6f;
  }
  __syncthreads();

  int wave = tid >> 6, lane = tid & 63;

  // ---- masked softmax: waves 0..TQ-1, one q-row each ----
  if (wave < TQ) {
    float m = -3.0e38f;
    #pragma unroll
    for (int j = 0; j < LK / 64; ++j) m = fmaxf(m, s_sc[wave][lane + j * 64]);
    #pragma unroll
    for (int off = 32; off; off >>= 1) m = fmaxf(m, __shfl_xor(m, off));
    float sum = 0.f;
    float vals[LK / 64];
    #pragma unroll
    for (int j = 0; j < LK / 64; ++j) {
      float e = fexp2((s_sc[wave][lane + j * 64] - m) * LOG2E);  // masked -> 0
      vals[j] = e;
      sum += e;
    }
    #pragma unroll
    for (int off = 32; off; off >>= 1) sum += __shfl_xor(sum, off);
    float inv = frcp(sum);
    #pragma unroll
    for (int j = 0; j < LK / 64; ++j) s_sc[wave][lane + j * 64] = vals[j] * inv;
  }
  __syncthreads();

  // ---- PV: wave w -> (row = w>>2, k-chunk = w&3); float2 over d; vlen-bounded ----
  {
    int row = wave >> 2, kc = wave & 3;
    int kend = min((((vlen + 3) >> 2) << 2), (kc + 1) * 128);
    const float2* vrow = (const float2*)(values + (size_t)b * LK * D_);
    float2 a = {0.f, 0.f};
    for (int kk = kc * 128; kk < kend; kk += 4) {
      float4 sc4 = *((const float4*)&s_sc[row][kk]);    // LDS broadcast
      float2 v0 = vrow[(size_t)(kk + 0) * 64 + lane];   // 512B/wave coalesced
      float2 v1 = vrow[(size_t)(kk + 1) * 64 + lane];
      float2 v2 = vrow[(size_t)(kk + 2) * 64 + lane];
      float2 v3 = vrow[(size_t)(kk + 3) * 64 + lane];
      a.x += sc4.x * v0.x + sc4.y * v1.x + sc4.z * v2.x + sc4.w * v3.x;
      a.y += sc4.x * v0.y + sc4.y * v1.y + sc4.z * v2.y + sc4.w * v3.y;
    }
    s_po[kc][row][2 * lane]     = a.x;
    s_po[kc][row][2 * lane + 1] = a.y;
  }
  __syncthreads();

  // ---- output projection: threads 0..255 cover TQ*H outputs ----
  if (tid < TQ * H_) {
    int ql = tid >> 7, h = tid & 127;
    float acc2 = 0.f;
    #pragma unroll 8
    for (int d = 0; d < D_; ++d) {
      float po = s_po[0][ql][d] + s_po[1][ql][d] + s_po[2][ql][d] + s_po[3][ql][d];
      acc2 = fmaf(po, Wo[d * H_ + h], acc2);           // coalesced, L2-hot
    }
    out[((size_t)b * LQ + q0 + ql) * H_ + h] = acc2;
  }
}

extern "C" void kernel_launch(void* const* d_in, const int* in_sizes, int n_in,
                              void* d_out, int out_size, void* d_ws, size_t ws_size,
                              hipStream_t stream) {
  const float* queries = (const float*)d_in[0];
  const float* keys    = (const float*)d_in[1];
  const float* values  = (const float*)d_in[2];
  const int*   vlen    = (const int*)d_in[3];
  const float* Wq      = (const float*)d_in[4];
  const float* Wk      = (const float*)d_in[5];
  const float* wv      = (const float*)d_in[6];
  const float* Wo      = (const float*)d_in[7];
  float* out = (float*)d_out;

  float* qproj = (float*)d_ws;                       // 1 MB, [row][h]
  float* kT    = qproj + (size_t)B_ * LQ * H_;       // 1 MB, [b][h][k]

  proj_kernel<<<dim3(B_ * (LQ + LK) / 8), 256, 0, stream>>>(queries, keys, Wq, Wk, qproj, kT);
  attn_kernel<<<dim3(LQ / TQ, B_), 512, 0, stream>>>(qproj, kT, values, vlen, wv, Wo, out);
}

// Round 7
// 143.275 us; speedup vs baseline: 1.0802x; 1.0802x over previous
//
#include <hip/hip_runtime.h>
#include <hip/hip_bf16.h>

#define B_   4
#define LQ   512
#define LK   512
#define D_   128
#define H_   128
#define LKP  576        // padded kT row stride (2304B: walks all L2 channels)
#define QS   4          // q-rows per score quantum / finish block

#define TWO_LOG2E 2.885390081777927f   // 2*log2(e)
#define LOG2E     1.442695040888963f

__device__ __forceinline__ float fexp2(float x) {
#if __has_builtin(__builtin_amdgcn_exp2f)
  return __builtin_amdgcn_exp2f(x);     // v_exp_f32 (native exp2)
#else
  return exp2f(x);
#endif
}
__device__ __forceinline__ float frcp(float x) {
#if __has_builtin(__builtin_amdgcn_rcpf)
  return __builtin_amdgcn_rcpf(x);      // v_rcp_f32
#else
  return __fdividef(1.0f, x);
#endif
}

// ---------------------------------------------------------------------------
// proj: 8 rows/block, 256 threads. qproj row-major [row][h];
// kT transposed+padded [b][h][k] stride LKP. Outputs pre-scaled by 2*log2e.
// ---------------------------------------------------------------------------
__global__ __launch_bounds__(256) void proj_kernel(
    const float* __restrict__ queries, const float* __restrict__ keys,
    const float* __restrict__ Wq, const float* __restrict__ Wk,
    float* __restrict__ qproj, float* __restrict__ kT) {
  __shared__ float s_x[8][D_];
  int r0 = blockIdx.x * 8;
  bool qside = r0 < B_ * LQ;
  const float* X = qside ? queries : keys;
  const float* W = qside ? Wq : Wk;
  int rb = qside ? r0 : r0 - B_ * LQ;
  int tid = threadIdx.x;
  for (int i = tid; i < 8 * D_; i += 256)
    s_x[i >> 7][i & 127] = X[(size_t)(rb + (i >> 7)) * D_ + (i & 127)];
  __syncthreads();
  int h = tid & 127, rh = tid >> 7;    // rows rh*4 .. rh*4+3
  const float4* x0 = (const float4*)s_x[rh * 4 + 0];
  const float4* x1 = (const float4*)s_x[rh * 4 + 1];
  const float4* x2 = (const float4*)s_x[rh * 4 + 2];
  const float4* x3 = (const float4*)s_x[rh * 4 + 3];
  float a0 = 0.f, a1 = 0.f, a2 = 0.f, a3 = 0.f;
  #pragma unroll 8
  for (int d4 = 0; d4 < D_ / 4; ++d4) {
    float4 xa = x0[d4], xb = x1[d4], xc = x2[d4], xd = x3[d4];  // ds_read_b128
    const float* Wd = W + 4 * d4 * H_ + h;
    float w0 = Wd[0], w1 = Wd[H_], w2 = Wd[2 * H_], w3 = Wd[3 * H_];  // coalesced
    a0 = fmaf(xa.x, w0, fmaf(xa.y, w1, fmaf(xa.z, w2, fmaf(xa.w, w3, a0))));
    a1 = fmaf(xb.x, w0, fmaf(xb.y, w1, fmaf(xb.z, w2, fmaf(xb.w, w3, a1))));
    a2 = fmaf(xc.x, w0, fmaf(xc.y, w1, fmaf(xc.z, w2, fmaf(xc.w, w3, a2))));
    a3 = fmaf(xd.x, w0, fmaf(xd.y, w1, fmaf(xd.z, w2, fmaf(xd.w, w3, a3))));
  }
  if (qside) {
    qproj[(size_t)(rb + rh * 4 + 0) * H_ + h] = a0 * TWO_LOG2E;
    qproj[(size_t)(rb + rh * 4 + 1) * H_ + h] = a1 * TWO_LOG2E;
    qproj[(size_t)(rb + rh * 4 + 2) * H_ + h] = a2 * TWO_LOG2E;
    qproj[(size_t)(rb + rh * 4 + 3) * H_ + h] = a3 * TWO_LOG2E;
  } else {
    int b = rb >> 9, kk = (rb & 511) + rh * 4;
    float* dst = kT + ((size_t)b * H_ + h) * LKP + kk;
    dst[0] = a0 * TWO_LOG2E;
    dst[1] = a1 * TWO_LOG2E;
    dst[2] = a2 * TWO_LOG2E;
    dst[3] = a3 * TWO_LOG2E;
  }
}

// ---------------------------------------------------------------------------
// score: one quantum per block = (batch, 4 q-rows, 256-k chunk).
// Grid 1024 blocks x 256 thr; batch is the FASTEST id digit -> every CU mixes
// batches; invalid quanta exit immediately (no parked waves, no vlen tails).
// score = sum_wv - 2 * sum_h wv_h * sigma_h,  sigma = 1/(1+exp2(q'+k')).
// Paired rcp: 1/d0 = d1*rcp(d0*d1), 1/d1 = d0*rcp(d0*d1).
// ---------------------------------------------------------------------------
__global__ __launch_bounds__(256) void score_kernel(
    const float* __restrict__ qproj, const float* __restrict__ kT,
    const int* __restrict__ vlen_arr, const float* __restrict__ wv,
    float* __restrict__ sc_g) {
  int id = blockIdx.x;
  int b = id & 3, kc = (id >> 2) & 1, qt = id >> 3;
  int vlen = vlen_arr[b];
  if (kc * 256 >= vlen) return;          // uniform early-exit (vlen>=1)

  __shared__ float s_q[QS][H_];          // 2 KB
  __shared__ float s_wv[H_];             // 0.5 KB
  int tid = threadIdx.x;
  for (int i = tid; i < QS * H_; i += 256)
    s_q[i >> 7][i & 127] = qproj[(size_t)(b * LQ + qt * QS + (i >> 7)) * H_ + (i & 127)];
  if (tid < H_) s_wv[tid] = wv[tid];
  __syncthreads();

  const float4* wv4p = (const float4*)s_wv;
  float sum_wv = 0.f;
  #pragma unroll
  for (int j = 0; j < H_ / 4; ++j) {
    float4 t4 = wv4p[j];
    sum_wv += t4.x + t4.y + t4.z + t4.w;
  }

  int k = kc * 256 + tid;
  if (k < vlen) {                        // boundary divergence in <=1 wave
    const float* kcol = kT + (size_t)b * H_ * LKP + k;
    const float4* qa4 = (const float4*)s_q[0];
    const float4* qb4 = (const float4*)s_q[1];
    const float4* qc4 = (const float4*)s_q[2];
    const float4* qd4 = (const float4*)s_q[3];
    float acc0 = 0.f, acc1 = 0.f, acc2 = 0.f, acc3 = 0.f;
    #pragma unroll 2
    for (int h4 = 0; h4 < H_ / 4; ++h4) {
      float kv0 = kcol[(size_t)(4 * h4 + 0) * LKP];   // 256B/wave coalesced, L2-hot
      float kv1 = kcol[(size_t)(4 * h4 + 1) * LKP];
      float kv2 = kcol[(size_t)(4 * h4 + 2) * LKP];
      float kv3 = kcol[(size_t)(4 * h4 + 3) * LKP];
      float4 w4 = wv4p[h4];
      float4 qa = qa4[h4], qb = qb4[h4], qc = qc4[h4], qd = qd4[h4];
      #pragma unroll
      for (int j = 0; j < 4; ++j) {
        float kv = (j == 0) ? kv0 : (j == 1) ? kv1 : (j == 2) ? kv2 : kv3;
        float w  = (j == 0) ? w4.x : (j == 1) ? w4.y : (j == 2) ? w4.z : w4.w;
        float xa = (j == 0) ? qa.x : (j == 1) ? qa.y : (j == 2) ? qa.z : qa.w;
        float xb = (j == 0) ? qb.x : (j == 1) ? qb.y : (j == 2) ? qb.z : qb.w;
        float xc = (j == 0) ? qc.x : (j == 1) ? qc.y : (j == 2) ? qc.z : qc.w;
        float xd = (j == 0) ? qd.x : (j == 1) ? qd.y : (j == 2) ? qd.z : qd.w;
        // pair rows (0,1): one rcp for two sigmoids
        float d0 = fexp2(xa + kv) + 1.f;
        float d1 = fexp2(xb + kv) + 1.f;
        float R01 = frcp(d0 * d1);
        acc0 = fmaf(w * d1, R01, acc0);
        acc1 = fmaf(w * d0, R01, acc1);
        // pair rows (2,3)
        float d2 = fexp2(xc + kv) + 1.f;
        float d3 = fexp2(xd + kv) + 1.f;
        float R23 = frcp(d2 * d3);
        acc2 = fmaf(w * d3, R23, acc2);
        acc3 = fmaf(w * d2, R23, acc3);
      }
    }
    float* dst = sc_g + (size_t)(b * LQ + qt * QS) * LK + k;
    dst[0 * LK] = fmaf(-2.f, acc0, sum_wv);
    dst[1 * LK] = fmaf(-2.f, acc1, sum_wv);
    dst[2 * LK] = fmaf(-2.f, acc2, sum_wv);
    dst[3 * LK] = fmaf(-2.f, acc3, sum_wv);
  }
}

// ---------------------------------------------------------------------------
// finish: softmax + PV + Wo projection. Grid (LQ/QS, B), 256 thr = 4 waves,
// wave w owns q-row w. All waves active in every phase.
// ---------------------------------------------------------------------------
__global__ __launch_bounds__(256) void finish_kernel(
    const float* __restrict__ sc_g, const float* __restrict__ values,
    const int* __restrict__ vlen_arr, const float* __restrict__ Wo,
    float* __restrict__ out) {
  int b = blockIdx.y, q0 = blockIdx.x * QS;
  int tid = threadIdx.x, wave = tid >> 6, lane = tid & 63;
  int vlen = vlen_arr[b];

  __shared__ float s_w[QS][LK];     // 8 KB normalized weights
  __shared__ float s_po[QS][D_];    // 2 KB PV result

  // ---- softmax for row (q0+wave), guarded to valid k only ----
  {
    const float* srow = sc_g + (size_t)(b * LQ + q0 + wave) * LK;
    float vals[LK / 64];
    float m = -3.0e38f;
    #pragma unroll
    for (int j = 0; j < LK / 64; ++j) {
      int k = lane + j * 64;
      float v = (k < vlen) ? srow[k] : -1.0e30f;   // predicated load; poison never read
      vals[j] = v;
      m = fmaxf(m, v);
    }
    #pragma unroll
    for (int off = 32; off; off >>= 1) m = fmaxf(m, __shfl_xor(m, off));
    float sum = 0.f;
    #pragma unroll
    for (int j = 0; j < LK / 64; ++j) {
      float e = fexp2((vals[j] - m) * LOG2E);      // invalid -> exp2(-huge) = 0
      vals[j] = e;
      sum += e;
    }
    #pragma unroll
    for (int off = 32; off; off >>= 1) sum += __shfl_xor(sum, off);
    float inv = frcp(sum);
    #pragma unroll
    for (int j = 0; j < LK / 64; ++j) s_w[wave][lane + j * 64] = vals[j] * inv;
  }
  __syncthreads();

  // ---- PV: wave w -> row w, float2 over d, vlen-bounded ----
  {
    int kend = (vlen + 3) & ~3;
    const float2* vrow = (const float2*)(values + (size_t)b * LK * D_);
    float2 a = {0.f, 0.f};
    for (int kk = 0; kk < kend; kk += 4) {
      float4 sc4 = *((const float4*)&s_w[wave][kk]);   // LDS broadcast
      float2 v0 = vrow[(size_t)(kk + 0) * 64 + lane];  // 512B/wave coalesced
      float2 v1 = vrow[(size_t)(kk + 1) * 64 + lane];
      float2 v2 = vrow[(size_t)(kk + 2) * 64 + lane];
      float2 v3 = vrow[(size_t)(kk + 3) * 64 + lane];
      a.x += sc4.x * v0.x + sc4.y * v1.x + sc4.z * v2.x + sc4.w * v3.x;
      a.y += sc4.x * v0.y + sc4.y * v1.y + sc4.z * v2.y + sc4.w * v3.y;
    }
    s_po[wave][2 * lane]     = a.x;
    s_po[wave][2 * lane + 1] = a.y;
  }
  __syncthreads();

  // ---- output projection: thread covers rows {qla, qla+2} at column h ----
  {
    int h = tid & 127, qla = tid >> 7, qlb = qla + 2;
    float aA = 0.f, aB = 0.f;
    #pragma unroll 8
    for (int d = 0; d < D_; ++d) {
      float w = Wo[d * H_ + h];                        // coalesced, L2-hot
      aA = fmaf(s_po[qla][d], w, aA);                  // LDS broadcasts
      aB = fmaf(s_po[qlb][d], w, aB);
    }
    out[(size_t)(b * LQ + q0 + qla) * H_ + h] = aA;
    out[(size_t)(b * LQ + q0 + qlb) * H_ + h] = aB;
  }
}

extern "C" void kernel_launch(void* const* d_in, const int* in_sizes, int n_in,
                              void* d_out, int out_size, void* d_ws, size_t ws_size,
                              hipStream_t stream) {
  const float* queries = (const float*)d_in[0];
  const float* keys    = (const float*)d_in[1];
  const float* values  = (const float*)d_in[2];
  const int*   vlen    = (const int*)d_in[3];
  const float* Wq      = (const float*)d_in[4];
  const float* Wk      = (const float*)d_in[5];
  const float* wv      = (const float*)d_in[6];
  const float* Wo      = (const float*)d_in[7];
  float* out = (float*)d_out;

  float* qproj = (float*)d_ws;                            // 1.00 MB [row][h]
  float* kT    = qproj + (size_t)B_ * LQ * H_;            // 1.13 MB [b][h][k] stride LKP
  float* sc_g  = kT + (size_t)B_ * H_ * LKP;              // 4.00 MB [b][q][k]

  proj_kernel<<<dim3(B_ * (LQ + LK) / 8), 256, 0, stream>>>(queries, keys, Wq, Wk, qproj, kT);
  score_kernel<<<dim3(B_ * 2 * (LQ / QS)), 256, 0, stream>>>(qproj, kT, vlen, wv, sc_g);
  finish_kernel<<<dim3(LQ / QS, B_), 256, 0, stream>>>(sc_g, values, vlen, Wo, out);
}

// Round 8
// 117.212 us; speedup vs baseline: 1.3204x; 1.2224x over previous
//
#include <hip/hip_runtime.h>
#include <hip/hip_bf16.h>

#define B_   4
#define LQ   512
#define LK   512
#define D_   128
#define H_   128
#define LKP  576        // padded EkT row stride (2304B)
#define QSS  2          // q-rows per score block
#define QSF  4          // q-rows per finish block

#define TWO_LOG2E 2.885390081777927f   // 2*log2(e)
#define LOG2E     1.442695040888963f

__device__ __forceinline__ float fexp2(float x) {
#if __has_builtin(__builtin_amdgcn_exp2f)
  return __builtin_amdgcn_exp2f(x);     // v_exp_f32 (native exp2)
#else
  return exp2f(x);
#endif
}
__device__ __forceinline__ float frcp(float x) {
#if __has_builtin(__builtin_amdgcn_rcpf)
  return __builtin_amdgcn_rcpf(x);      // v_rcp_f32
#else
  return __fdividef(1.0f, x);
#endif
}

// 4 sigmoid-accumulations sharing 2 rcp: rows A,B x k-pair ek.
// d = 1 + eq*ek;  acc += w/d  via paired reciprocal.
__device__ __forceinline__ void sig4(float eqa, float eqb, float w, float2 ek,
                                     float& aA0, float& aA1, float& aB0, float& aB1) {
  float dA0 = fmaf(eqa, ek.x, 1.f);
  float dA1 = fmaf(eqa, ek.y, 1.f);
  float RA  = frcp(dA0 * dA1);
  aA0 = fmaf(w * dA1, RA, aA0);
  aA1 = fmaf(w * dA0, RA, aA1);
  float dB0 = fmaf(eqb, ek.x, 1.f);
  float dB1 = fmaf(eqb, ek.y, 1.f);
  float RB  = frcp(dB0 * dB1);
  aB0 = fmaf(w * dB1, RB, aB0);
  aB1 = fmaf(w * dB0, RB, aB1);
}

// ---------------------------------------------------------------------------
// proj: 8 rows/block, 256 threads.
// Outputs EXPONENTIALS of the pre-scaled projections:
//   Eq  [row][h]      = exp2(2*log2e * q.Wq)
//   EkT [b][h][k]     = exp2(2*log2e * k.Wk), transposed, stride LKP.
// Then exp2(q'+k') = Eq*Ek -> score kernel needs NO exp at all.
// ---------------------------------------------------------------------------
__global__ __launch_bounds__(256) void proj_kernel(
    const float* __restrict__ queries, const float* __restrict__ keys,
    const float* __restrict__ Wq, const float* __restrict__ Wk,
    float* __restrict__ Eq, float* __restrict__ EkT) {
  __shared__ float s_x[8][D_];
  int r0 = blockIdx.x * 8;
  bool qside = r0 < B_ * LQ;
  const float* X = qside ? queries : keys;
  const float* W = qside ? Wq : Wk;
  int rb = qside ? r0 : r0 - B_ * LQ;
  int tid = threadIdx.x;
  for (int i = tid; i < 8 * D_; i += 256)
    s_x[i >> 7][i & 127] = X[(size_t)(rb + (i >> 7)) * D_ + (i & 127)];
  __syncthreads();
  int h = tid & 127, rh = tid >> 7;    // rows rh*4 .. rh*4+3
  const float4* x0 = (const float4*)s_x[rh * 4 + 0];
  const float4* x1 = (const float4*)s_x[rh * 4 + 1];
  const float4* x2 = (const float4*)s_x[rh * 4 + 2];
  const float4* x3 = (const float4*)s_x[rh * 4 + 3];
  float a0 = 0.f, a1 = 0.f, a2 = 0.f, a3 = 0.f;
  #pragma unroll 8
  for (int d4 = 0; d4 < D_ / 4; ++d4) {
    float4 xa = x0[d4], xb = x1[d4], xc = x2[d4], xd = x3[d4];  // ds_read_b128
    const float* Wd = W + 4 * d4 * H_ + h;
    float w0 = Wd[0], w1 = Wd[H_], w2 = Wd[2 * H_], w3 = Wd[3 * H_];  // coalesced
    a0 = fmaf(xa.x, w0, fmaf(xa.y, w1, fmaf(xa.z, w2, fmaf(xa.w, w3, a0))));
    a1 = fmaf(xb.x, w0, fmaf(xb.y, w1, fmaf(xb.z, w2, fmaf(xb.w, w3, a1))));
    a2 = fmaf(xc.x, w0, fmaf(xc.y, w1, fmaf(xc.z, w2, fmaf(xc.w, w3, a2))));
    a3 = fmaf(xd.x, w0, fmaf(xd.y, w1, fmaf(xd.z, w2, fmaf(xd.w, w3, a3))));
  }
  if (qside) {
    Eq[(size_t)(rb + rh * 4 + 0) * H_ + h] = fexp2(a0 * TWO_LOG2E);
    Eq[(size_t)(rb + rh * 4 + 1) * H_ + h] = fexp2(a1 * TWO_LOG2E);
    Eq[(size_t)(rb + rh * 4 + 2) * H_ + h] = fexp2(a2 * TWO_LOG2E);
    Eq[(size_t)(rb + rh * 4 + 3) * H_ + h] = fexp2(a3 * TWO_LOG2E);
  } else {
    int b = rb >> 9, kk = (rb & 511) + rh * 4;
    float* dst = EkT + ((size_t)b * H_ + h) * LKP + kk;
    dst[0] = fexp2(a0 * TWO_LOG2E);
    dst[1] = fexp2(a1 * TWO_LOG2E);
    dst[2] = fexp2(a2 * TWO_LOG2E);
    dst[3] = fexp2(a3 * TWO_LOG2E);
  }
}

// ---------------------------------------------------------------------------
// score: block = (b, 2 q-rows); thread owns k-PAIR {2t, 2t+1} (float2 loads,
// 8B/lane coalescing sweet spot). Grid 1024, b = fastest digit (CU balance).
// NO exp in loop: d = 1 + Eq*Ek; paired rcp (2 per 4 sigmoids).
// score = sum_wv - 2 * sum_h wv_h / d_h.  Threads past vlen exit early.
// ---------------------------------------------------------------------------
__global__ __launch_bounds__(256) void score_kernel(
    const float* __restrict__ Eq, const float* __restrict__ EkT,
    const int* __restrict__ vlen_arr, const float* __restrict__ wv,
    float* __restrict__ sc_g) {
  int id = blockIdx.x;
  int b = id & 3, q0 = (id >> 2) * QSS;
  int tid = threadIdx.x;

  __shared__ float s_eq[QSS][H_];   // 1 KB
  __shared__ float s_wv[H_];        // 0.5 KB

  s_eq[tid >> 7][tid & 127] = Eq[(size_t)(b * LQ + q0 + (tid >> 7)) * H_ + (tid & 127)];
  if (tid < H_) s_wv[tid] = wv[tid];
  __syncthreads();
  int vlen = vlen_arr[b];

  const float4* wv4p = (const float4*)s_wv;
  float sum_wv = 0.f;
  #pragma unroll
  for (int j = 0; j < H_ / 4; ++j) {
    float4 t4 = wv4p[j];
    sum_wv += t4.x + t4.y + t4.z + t4.w;
  }

  int k0 = tid * 2;
  if (k0 < vlen) {                   // waves fully past vlen exit (no barrier below)
    const float2* ek2 = (const float2*)(EkT + (size_t)b * H_ * LKP);
    const float4* eqa4 = (const float4*)s_eq[0];
    const float4* eqb4 = (const float4*)s_eq[1];
    float aA0 = 0.f, aA1 = 0.f, aB0 = 0.f, aB1 = 0.f;
    #pragma unroll 2
    for (int h4 = 0; h4 < H_ / 4; ++h4) {
      float2 e0 = ek2[(size_t)(4 * h4 + 0) * (LKP / 2) + tid];  // 512B/wave coalesced
      float2 e1 = ek2[(size_t)(4 * h4 + 1) * (LKP / 2) + tid];
      float2 e2 = ek2[(size_t)(4 * h4 + 2) * (LKP / 2) + tid];
      float2 e3 = ek2[(size_t)(4 * h4 + 3) * (LKP / 2) + tid];
      float4 w4 = wv4p[h4];          // LDS broadcasts
      float4 qa = eqa4[h4];
      float4 qb = eqb4[h4];
      sig4(qa.x, qb.x, w4.x, e0, aA0, aA1, aB0, aB1);
      sig4(qa.y, qb.y, w4.y, e1, aA0, aA1, aB0, aB1);
      sig4(qa.z, qb.z, w4.z, e2, aA0, aA1, aB0, aB1);
      sig4(qa.w, qb.w, w4.w, e3, aA0, aA1, aB0, aB1);
    }
    // k1 >= vlen garbage is never read downstream (finish guards by vlen)
    float2 rA = { fmaf(-2.f, aA0, sum_wv), fmaf(-2.f, aA1, sum_wv) };
    float2 rB = { fmaf(-2.f, aB0, sum_wv), fmaf(-2.f, aB1, sum_wv) };
    ((float2*)(sc_g + (size_t)(b * LQ + q0 + 0) * LK))[tid] = rA;
    ((float2*)(sc_g + (size_t)(b * LQ + q0 + 1) * LK))[tid] = rB;
  }
}

// ---------------------------------------------------------------------------
// finish: block = (b, 4 q-rows), 256 thr = 4 waves, b = fastest grid digit.
// softmax: wave w -> row w.  PV: wave w -> k-chunk w for ALL 4 rows (V read
// once per block, 4x less L2 traffic than row-per-wave).  Then Wo projection.
// ---------------------------------------------------------------------------
__global__ __launch_bounds__(256) void finish_kernel(
    const float* __restrict__ sc_g, const float* __restrict__ values,
    const int* __restrict__ vlen_arr, const float* __restrict__ Wo,
    float* __restrict__ out) {
  int id = blockIdx.x;
  int b = id & 3, q0 = (id >> 2) * QSF;
  int tid = threadIdx.x, wave = tid >> 6, lane = tid & 63;
  int vlen = vlen_arr[b];

  __shared__ float s_w[QSF][LK];        // 8 KB normalized weights (0 for k>=vlen)
  __shared__ float s_po[QSF][QSF][D_];  // 8 KB [chunk][row][d] PV partials
  __shared__ float s_pr[QSF][D_];       // 2 KB reduced PV

  // ---- softmax: wave w -> row q0+w, guarded to valid k ----
  {
    const float* srow = sc_g + (size_t)(b * LQ + q0 + wave) * LK;
    float vals[LK / 64];
    float m = -3.0e38f;
    #pragma unroll
    for (int j = 0; j < LK / 64; ++j) {
      int k = lane + j * 64;
      float v = (k < vlen) ? srow[k] : -1.0e30f;
      vals[j] = v;
      m = fmaxf(m, v);
    }
    #pragma unroll
    for (int off = 32; off; off >>= 1) m = fmaxf(m, __shfl_xor(m, off));
    float sum = 0.f;
    #pragma unroll
    for (int j = 0; j < LK / 64; ++j) {
      float e = fexp2((vals[j] - m) * LOG2E);   // invalid -> 0
      vals[j] = e;
      sum += e;
    }
    #pragma unroll
    for (int off = 32; off; off >>= 1) sum += __shfl_xor(sum, off);
    float inv = frcp(sum);
    #pragma unroll
    for (int j = 0; j < LK / 64; ++j) s_w[wave][lane + j * 64] = vals[j] * inv;
  }
  __syncthreads();

  // ---- PV: wave w -> k-chunk [128w, 128w+128) for ALL rows; V read once ----
  {
    int kbeg = wave * 128;
    int kend = min((vlen + 3) & ~3, kbeg + 128);   // weights are 0 past vlen
    const float2* vrow = (const float2*)(values + (size_t)b * LK * D_);
    float2 a0 = {0.f, 0.f}, a1 = {0.f, 0.f}, a2 = {0.f, 0.f}, a3 = {0.f, 0.f};
    #pragma unroll 2
    for (int kk = kbeg; kk < kend; kk += 4) {
      float2 v0 = vrow[(size_t)(kk + 0) * 64 + lane];   // 512B/wave coalesced
      float2 v1 = vrow[(size_t)(kk + 1) * 64 + lane];
      float2 v2 = vrow[(size_t)(kk + 2) * 64 + lane];
      float2 v3 = vrow[(size_t)(kk + 3) * 64 + lane];
      float4 w0 = *(const float4*)&s_w[0][kk];          // LDS broadcasts
      float4 w1 = *(const float4*)&s_w[1][kk];
      float4 w2 = *(const float4*)&s_w[2][kk];
      float4 w3 = *(const float4*)&s_w[3][kk];
      a0.x += w0.x * v0.x + w0.y * v1.x + w0.z * v2.x + w0.w * v3.x;
      a0.y += w0.x * v0.y + w0.y * v1.y + w0.z * v2.y + w0.w * v3.y;
      a1.x += w1.x * v0.x + w1.y * v1.x + w1.z * v2.x + w1.w * v3.x;
      a1.y += w1.x * v0.y + w1.y * v1.y + w1.z * v2.y + w1.w * v3.y;
      a2.x += w2.x * v0.x + w2.y * v1.x + w2.z * v2.x + w2.w * v3.x;
      a2.y += w2.x * v0.y + w2.y * v1.y + w2.z * v2.y + w2.w * v3.y;
      a3.x += w3.x * v0.x + w3.y * v1.x + w3.z * v2.x + w3.w * v3.x;
      a3.y += w3.x * v0.y + w3.y * v1.y + w3.z * v2.y + w3.w * v3.y;
    }
    s_po[wave][0][2 * lane] = a0.x; s_po[wave][0][2 * lane + 1] = a0.y;  // 2-way alias: free
    s_po[wave][1][2 * lane] = a1.x; s_po[wave][1][2 * lane + 1] = a1.y;
    s_po[wave][2][2 * lane] = a2.x; s_po[wave][2][2 * lane + 1] = a2.y;
    s_po[wave][3][2 * lane] = a3.x; s_po[wave][3][2 * lane + 1] = a3.y;
  }
  __syncthreads();

  // ---- reduce chunk partials: 512 elems over 256 threads ----
  #pragma unroll
  for (int i = tid; i < QSF * D_; i += 256) {
    int r = i >> 7, d = i & 127;
    s_pr[r][d] = s_po[0][r][d] + s_po[1][r][d] + s_po[2][r][d] + s_po[3][r][d];
  }
  __syncthreads();

  // ---- output projection: thread -> col h, rows {r, r+2} ----
  {
    int h = tid & 127, r = tid >> 7;
    float accA = 0.f, accB = 0.f;
    #pragma unroll 8
    for (int d = 0; d < D_; ++d) {
      float w = Wo[d * H_ + h];                  // coalesced, L2-hot
      accA = fmaf(s_pr[r][d], w, accA);          // LDS broadcasts
      accB = fmaf(s_pr[r + 2][d], w, accB);
    }
    out[(size_t)(b * LQ + q0 + r) * H_ + h] = accA;
    out[(size_t)(b * LQ + q0 + r + 2) * H_ + h] = accB;
  }
}

extern "C" void kernel_launch(void* const* d_in, const int* in_sizes, int n_in,
                              void* d_out, int out_size, void* d_ws, size_t ws_size,
                              hipStream_t stream) {
  const float* queries = (const float*)d_in[0];
  const float* keys    = (const float*)d_in[1];
  const float* values  = (const float*)d_in[2];
  const int*   vlen    = (const int*)d_in[3];
  const float* Wq      = (const float*)d_in[4];
  const float* Wk      = (const float*)d_in[5];
  const float* wv      = (const float*)d_in[6];
  const float* Wo      = (const float*)d_in[7];
  float* out = (float*)d_out;

  float* Eq   = (float*)d_ws;                           // 1.00 MB [row][h]
  float* EkT  = Eq + (size_t)B_ * LQ * H_;              // 1.13 MB [b][h][k] stride LKP
  float* sc_g = EkT + (size_t)B_ * H_ * LKP;            // 4.00 MB [b][q][k]

  proj_kernel<<<dim3(B_ * (LQ + LK) / 8), 256, 0, stream>>>(queries, keys, Wq, Wk, Eq, EkT);
  score_kernel<<<dim3(B_ * (LQ / QSS)), 256, 0, stream>>>(Eq, EkT, vlen, wv, sc_g);
  finish_kernel<<<dim3(B_ * (LQ / QSF)), 256, 0, stream>>>(sc_g, values, vlen, Wo, out);
}